// Round 10
// baseline (197.723 us; speedup 1.0000x reference)
//
#include <hip/hip_runtime.h>
#include <stdint.h>
#include <stddef.h>

// GA3 conv2d == one dense 3x3 conv with sign-permuted weights:
//   out[b, c*8+m, h, w] = bias_eff[c*8+m]
//     + sum_{cin,k,kh,kw} s(m,k) * W[j(m,k),c,cin,kh,kw] * x[b, cin*8+k, h+kh-1, w+kw-1]
// bf16 MFMA implicit GEMM over 9 taps (K=128 each).
// R7: lds_x DELETED -- A fragments load directly from xt (L2-hot; conv's VMEM pipe
// was ~1% utilized while the LDS pipe carried ~23us of A+B reads). LDS = 32KB lds_w
// only -> 4 blocks/CU (16 waves, 2x TLP), grid 1024 = exactly one uniform batch.
// B stays per-tap in lds_w via global_load_lds (R6 cadence, zero VGPR cost).
// R6 evidence: B-from-LDS == B-from-global ==> latency wasn't B; LDS BW + TLP were.

typedef __attribute__((ext_vector_type(8))) short short8;   // 8 x bf16 (4 VGPRs)
typedef __attribute__((ext_vector_type(4))) float f32x4;    // MFMA accumulator

#define GLD_LDS16(gsrc, ldst) __builtin_amdgcn_global_load_lds( \
    (const __attribute__((address_space(1))) void*)(gsrc),      \
    (__attribute__((address_space(3))) void*)(ldst), 16, 0, 0)

// j(m,k) and s(m,k): unique j with S[m,j,k]!=0, transcribed from _TERMS.
__device__ __constant__ int c_J[64] = {
  0,1,2,3,4,5,6,7,
  1,0,4,6,2,7,3,5,
  2,4,0,5,1,3,7,6,
  3,6,5,0,7,2,1,4,
  4,2,1,7,0,6,5,3,
  5,7,3,2,6,0,4,1,
  6,3,7,1,5,4,0,2,
  7,5,6,4,3,1,2,0
};
__device__ __constant__ float c_Sg[64] = {
  1,1,1,1,-1,-1,-1,-1,
  1,1,-1,-1,1,-1,1,-1,
  1,1,1,-1,-1,1,1,1,
  1,1,1,1,-1,-1,-1,-1,
  1,1,-1,1,1,1,-1,1,
  1,1,1,-1,-1,1,1,1,
  1,1,-1,-1,1,-1,1,-1,
  1,1,-1,1,1,1,-1,1
};

__device__ inline unsigned short f2bf(float f) {  // RNE float->bf16
  unsigned int u = __float_as_uint(f);
  u += 0x7FFFu + ((u >> 16) & 1u);
  return (unsigned short)(u >> 16);
}

// ---------------- Prep A: x [8][128][128][128] f32 NCHW -> xt [8][130][130][128] bf16 NHWC
// (padded). One block per (h, b): full 128-w row, all 128 ic. float4 reads,
// LDS [ic][stride 129] (odd stride: both phases 2-way = free), uint2 writes.
// Border zeroing folded in: col 0/129 every block; rows 0/129 in h==0/127 blocks.
__global__ __launch_bounds__(256) void xpose_kernel(const float* __restrict__ x,
                                                    unsigned short* __restrict__ xt) {
  __shared__ unsigned short t[128 * 129];   // 33,024 B
  const int h   = blockIdx.x;       // 0..127
  const int b   = blockIdx.y;       // 0..7
  const int tid = threadIdx.x;
  // Phase 1: global float4 -> bf16 -> LDS [ic][w]
  #pragma unroll
  for (int i = 0; i < 16; ++i) {
    int idx = tid + i * 256;        // 0..4095 = 128 ic * 32 w-quads
    int ic = idx >> 5, wq = idx & 31;
    const float4 v = *(const float4*)(x + ((size_t)(b * 128 + ic) * 128 + h) * 128 + 4 * wq);
    unsigned short* d = t + ic * 129 + 4 * wq;
    d[0] = f2bf(v.x); d[1] = f2bf(v.y); d[2] = f2bf(v.z); d[3] = f2bf(v.w);
  }
  // Border: cols 0 and 129 of this row (h+1)
  if (tid < 128) {
    int c = tid >> 6, u = tid & 63;
    *(unsigned int*)(xt + ((size_t)(b * 130 + h + 1) * 130 + c * 129) * 128 + 2 * u) = 0u;
  }
  // Border: rows 0 / 129 (only the h==0 / h==127 blocks)
  if (h == 0 || h == 127) {
    int row = (h == 0) ? 0 : 129;
    for (int i = 0; i < 33; ++i) {
      int idx = tid + i * 256;      // 130 px * 64 uints = 8320
      if (idx < 8320) {
        int w = idx >> 6, u = idx & 63;
        *(unsigned int*)(xt + ((size_t)(b * 130 + row) * 130 + w) * 128 + 2 * u) = 0u;
      }
    }
  }
  __syncthreads();
  // Phase 2: LDS -> global, ic-contiguous uint2 (4 ic per lane per iter)
  #pragma unroll
  for (int i = 0; i < 16; ++i) {
    int idx = tid + i * 256;        // 0..4095 = 128 w * 32 ic-quads
    int w = idx >> 5, p4 = idx & 31;
    unsigned int s0 = t[(4 * p4 + 0) * 129 + w];
    unsigned int s1 = t[(4 * p4 + 1) * 129 + w];
    unsigned int s2 = t[(4 * p4 + 2) * 129 + w];
    unsigned int s3 = t[(4 * p4 + 3) * 129 + w];
    uint2 o; o.x = s0 | (s1 << 16); o.y = s2 | (s3 << 16);
    *(uint2*)(xt + ((size_t)(b * 130 + h + 1) * 130 + (w + 1)) * 128 + 4 * p4) = o;
  }
}

// ---------------- Prep B: vt[t][ks][ocb][lane][8] bf16 — tap t's 32KB block is a flat
// [ks][ocb][512-short] region (copied whole into LDS by conv): oc = ocb*16 + (lane&15),
// ic = ks*32 + (lane>>4)*8 + e.  Also bias_eff[128] f32.
__global__ __launch_bounds__(256) void prep_kernel(const float* __restrict__ W,
                                                   const float* __restrict__ bias,
                                                   unsigned short* __restrict__ vt,
                                                   float* __restrict__ beff) {
  int gid = blockIdx.x * 256 + threadIdx.x;   // 9*128*128 = 147456 threads exactly
  int t   = gid >> 14;
  int rem = gid & 16383;
  int oc  = rem >> 7;
  int ic  = rem & 127;
  int m = oc & 7, cout = oc >> 3;
  int k = ic & 7, cin = ic >> 3;
  int j = c_J[m * 8 + k];
  float s = c_Sg[m * 8 + k];
  float val = s * W[((j * 16 + cout) * 16 + cin) * 9 + t];
  int ks = ic >> 5, quad = (ic >> 3) & 3, e = ic & 7;
  int ocb = oc >> 4, l15 = oc & 15;
  vt[(size_t)((t * 4 + ks) * 8 + ocb) * 512 + (quad * 16 + l15) * 8 + e] = f2bf(val);
  if (gid < 128) {
    int m2 = gid & 7, cout2 = gid >> 3;
    float acc = 0.f;
    #pragma unroll
    for (int kk = 0; kk < 8; ++kk)
      acc += c_Sg[m2 * 8 + kk] * bias[c_J[m2 * 8 + kk] * 16 + cout2];
    beff[gid] = acc;
  }
}

// ---------------- Main: tap-decomposed implicit GEMM, bf16 MFMA 16x16x32 ----------------
// Block: 256 thr = 4 waves. Tile: 8 rows x 16 cols of output pixels x all 128 oc.
// A fragments: DIRECT global loads from xt (L2-hot; each wave-load = 16 x 64B segments).
// B: current tap's 32KB of vt in lds_w via global_load_lds (async, no VGPRs);
// per tap: barrier -> 8x global_load_lds -> vmcnt(0) -> barrier -> 4ks x 16 MFMA.
// LDS 32KB + VGPR<=128 -> 4 blocks/CU (16 waves); grid 1024 = one uniform batch.
__global__ __launch_bounds__(256) void conv_kernel(const unsigned short* __restrict__ xt,
                                                   const unsigned short* __restrict__ vt,
                                                   const float* __restrict__ beff,
                                                   float* __restrict__ out) {
  __shared__ __align__(16) unsigned short lds_w[128 * 128];   // one tap of B, 32 KiB
  const int tid  = threadIdx.x;
  const int bx   = blockIdx.x;    // 0..7   w tile (16)
  const int by   = blockIdx.y;    // 0..15  h tile (8)
  const int b    = blockIdx.z;    // 0..7
  const int lane = tid & 63;
  const int wave = tid >> 6;
  const int wm   = wave >> 1;     // 0..1
  const int wn   = wave & 1;      // 0..1
  const int l15  = lane & 15;
  const int quad = lane >> 4;

  // Stage tap-0 B: async direct-to-LDS.
  #pragma unroll
  for (int i = 0; i < 8; ++i) {
    int c = (tid + i * 256) * 16;   // byte offset; wave-uniform base + lane*16
    GLD_LDS16((const char*)vt + c, (char*)lds_w + c);
  }
  asm volatile("s_waitcnt vmcnt(0)" ::: "memory");
  __syncthreads();                  // tap-0 B ready

  f32x4 acc[4][4];
  #pragma unroll
  for (int mi = 0; mi < 4; ++mi)
    #pragma unroll
    for (int ni = 0; ni < 4; ++ni)
      acc[mi][ni] = f32x4{0.f, 0.f, 0.f, 0.f};

  // Per-lane A base: padded halo origin (row by*8, col bx*16) + this lane's col/k slot.
  // A(mi,dh,dw,ks) = xa + ((wm*4+mi+dh)*130 + dw)*128 + ks*32   (shorts)
  const unsigned short* xa = xt + ((size_t)(b * 130 + by * 8) * 130 + bx * 16) * 128
                                + (size_t)l15 * 128 + quad * 8;

  #pragma unroll
  for (int t = 0; t < 9; ++t) {
    const int dh = t / 3, dw = t % 3;
    #pragma unroll
    for (int ks = 0; ks < 4; ++ks) {                   // K = 128 = 4 x 32
      short8 bb[4];
      #pragma unroll
      for (int ni = 0; ni < 4; ++ni)                   // contiguous 1KB/wave, conflict-free
        bb[ni] = *(const short8*)(lds_w + (ks * 8 + wn * 4 + ni) * 512 + lane * 8);
      short8 a[4];
      #pragma unroll
      for (int mi = 0; mi < 4; ++mi)                   // direct from xt: 16 x 64B segs, L2-hot
        a[mi] = *(const short8*)(xa + ((wm * 4 + mi + dh) * 130 + dw) * 128 + ks * 32);
      #pragma unroll
      for (int mi = 0; mi < 4; ++mi)
        #pragma unroll
        for (int ni = 0; ni < 4; ++ni)
          acc[mi][ni] = __builtin_amdgcn_mfma_f32_16x16x32_bf16(a[mi], bb[ni], acc[mi][ni], 0, 0, 0);
    }
    if (t < 8) {
      __syncthreads();             // all waves done reading lds_w for tap t
      const char* src = (const char*)vt + (size_t)(t + 1) * 32768;
      #pragma unroll
      for (int i = 0; i < 8; ++i) {
        int c = (tid + i * 256) * 16;
        GLD_LDS16(src + c, (char*)lds_w + c);
      }
      asm volatile("s_waitcnt vmcnt(0)" ::: "memory");
      __syncthreads();             // tap t+1 B ready
    }
  }

  // Epilogue: D row = quad*4+reg (pixel w offset), col = l15 (oc). float4 stores, w-contiguous.
  const int h0 = by * 8, w0 = bx * 16;
  #pragma unroll
  for (int ni = 0; ni < 4; ++ni) {
    int oc = (wn * 4 + ni) * 16 + l15;
    float bv = beff[oc];
    #pragma unroll
    for (int mi = 0; mi < 4; ++mi) {
      int h = h0 + wm * 4 + mi;
      int w = w0 + quad * 4;
      f32x4 v = acc[mi][ni];
      v[0] += bv; v[1] += bv; v[2] += bv; v[3] += bv;
      *(f32x4*)(out + ((size_t)(b * 128 + oc) * 128 + h) * 128 + w) = v;
    }
  }
}

extern "C" void kernel_launch(void* const* d_in, const int* in_sizes, int n_in,
                              void* d_out, int out_size, void* d_ws, size_t ws_size,
                              hipStream_t stream) {
  (void)in_sizes; (void)n_in; (void)out_size; (void)ws_size;
  const float* x    = (const float*)d_in[0];   // [8][128][128][128]
  const float* W    = (const float*)d_in[1];   // [8][16][16][3][3]
  const float* bias = (const float*)d_in[2];   // [8][16]
  float* out = (float*)d_out;                  // [8][128][128][128]

  const size_t XT_BYTES = (size_t)8 * 130 * 130 * 128 * 2;   // 34,611,200
  const size_t VT_BYTES = (size_t)9 * 4 * 8 * 512 * 2;       //    294,912
  unsigned short* xt = (unsigned short*)d_ws;
  unsigned short* vt = (unsigned short*)((char*)d_ws + XT_BYTES);
  float* beff = (float*)((char*)d_ws + XT_BYTES + VT_BYTES);

  prep_kernel<<<dim3(576), 256, 0, stream>>>(W, bias, vt, beff);       // vt + beff
  xpose_kernel<<<dim3(128, 8), 256, 0, stream>>>(x, xt);               // incl. border zero
  conv_kernel<<<dim3(8, 16, 8), 256, 0, stream>>>(xt, vt, beff, out);
}

// Round 11
// 165.020 us; speedup vs baseline: 1.1982x; 1.1982x over previous
//
#include <hip/hip_runtime.h>
#include <stdint.h>
#include <stddef.h>

// GA3 conv2d == one dense 3x3 conv with sign-permuted weights:
//   out[b, c*8+m, h, w] = bias_eff[c*8+m]
//     + sum_{cin,k,kh,kw} s(m,k) * W[j(m,k),c,cin,kh,kw] * x[b, cin*8+k, h+kh-1, w+kw-1]
// bf16 MFMA implicit GEMM over 9 taps (K=128 each).
// R8: xpose kernel DELETED -- conv stages its halo tile directly from x (f32 NCHW),
// doing transpose + bf16-convert + XOR-swizzle in-block (VALU was 6-14% idle).
// Kills the 67MB xt round-trip, the xpose dispatch, and its launch gap; borders
// become load predicates. MFMA core + lds_w global_load_lds cadence = R6 verbatim
// (best measured conv, 48us). Pipeline is now 2 kernels: prep -> conv.
// R7 lesson: A-fragments MUST come from LDS (9x tap reuse); only the FILL changed.

typedef __attribute__((ext_vector_type(8))) short short8;   // 8 x bf16 (4 VGPRs)
typedef __attribute__((ext_vector_type(4))) float f32x4;    // MFMA accumulator

#define GLD_LDS16(gsrc, ldst) __builtin_amdgcn_global_load_lds( \
    (const __attribute__((address_space(1))) void*)(gsrc),      \
    (__attribute__((address_space(3))) void*)(ldst), 16, 0, 0)

// j(m,k) and s(m,k): unique j with S[m,j,k]!=0, transcribed from _TERMS.
__device__ __constant__ int c_J[64] = {
  0,1,2,3,4,5,6,7,
  1,0,4,6,2,7,3,5,
  2,4,0,5,1,3,7,6,
  3,6,5,0,7,2,1,4,
  4,2,1,7,0,6,5,3,
  5,7,3,2,6,0,4,1,
  6,3,7,1,5,4,0,2,
  7,5,6,4,3,1,2,0
};
__device__ __constant__ float c_Sg[64] = {
  1,1,1,1,-1,-1,-1,-1,
  1,1,-1,-1,1,-1,1,-1,
  1,1,1,-1,-1,1,1,1,
  1,1,1,1,-1,-1,-1,-1,
  1,1,-1,1,1,1,-1,1,
  1,1,1,-1,-1,1,1,1,
  1,1,-1,-1,1,-1,1,-1,
  1,1,-1,1,1,1,-1,1
};

__device__ inline unsigned short f2bf(float f) {  // RNE float->bf16
  unsigned int u = __float_as_uint(f);
  u += 0x7FFFu + ((u >> 16) & 1u);
  return (unsigned short)(u >> 16);
}

// ---------------- Prep: vt[t][ks][ocb][lane][8] bf16 — tap t's 32KB block is a flat
// [ks][ocb][512-short] region (copied whole into LDS by conv): oc = ocb*16 + (lane&15),
// ic = ks*32 + (lane>>4)*8 + e.  Also bias_eff[128] f32.
__global__ __launch_bounds__(256) void prep_kernel(const float* __restrict__ W,
                                                   const float* __restrict__ bias,
                                                   unsigned short* __restrict__ vt,
                                                   float* __restrict__ beff) {
  int gid = blockIdx.x * 256 + threadIdx.x;   // 9*128*128 = 147456 threads exactly
  int t   = gid >> 14;
  int rem = gid & 16383;
  int oc  = rem >> 7;
  int ic  = rem & 127;
  int m = oc & 7, cout = oc >> 3;
  int k = ic & 7, cin = ic >> 3;
  int j = c_J[m * 8 + k];
  float s = c_Sg[m * 8 + k];
  float val = s * W[((j * 16 + cout) * 16 + cin) * 9 + t];
  int ks = ic >> 5, quad = (ic >> 3) & 3, e = ic & 7;
  int ocb = oc >> 4, l15 = oc & 15;
  vt[(size_t)((t * 4 + ks) * 8 + ocb) * 512 + (quad * 16 + l15) * 8 + e] = f2bf(val);
  if (gid < 128) {
    int m2 = gid & 7, cout2 = gid >> 3;
    float acc = 0.f;
    #pragma unroll
    for (int kk = 0; kk < 8; ++kk)
      acc += c_Sg[m2 * 8 + kk] * bias[c_J[m2 * 8 + kk] * 16 + cout2];
    beff[gid] = acc;
  }
}

// ---------------- Main: fused transpose + tap-decomposed implicit GEMM ----------------
// Block: 256 thr = 4 waves. Tile: 8 rows x 16 cols of output pixels x all 128 oc.
// Staging: 1280 (hh,ic) slots; each loads 18 w-contiguous f32 from x (4 float4 + 2
// predicated scalars), converts to bf16, scalar-writes transposed into swizzled lds_x
// (lanes = consecutive ic -> 2 lanes/bank = free). h/w out-of-range -> zeros (padding).
// lds_x layout/swizzle and the whole MFMA loop are identical to R6:
//   chunk c at uint4 index c ^ ((c>>4)&7), row = c>>4 = hh*18+ww.
// B: current tap's 32KB of vt in lds_w via global_load_lds (async, zero VGPR).
// LDS 45+32=78.8KB -> 2 blocks/CU.
__global__ __launch_bounds__(256) void conv_kernel(const float* __restrict__ x,
                                                   const unsigned short* __restrict__ vt,
                                                   const float* __restrict__ beff,
                                                   float* __restrict__ out) {
  __shared__ __align__(16) unsigned short lds_x[10 * 18 * 128]; // halo [hh][ww][ic], 45 KiB
  __shared__ __align__(16) unsigned short lds_w[128 * 128];     // one tap of B, 32 KiB
  const int tid  = threadIdx.x;
  const int bx   = blockIdx.x;    // 0..7   w tile (16)
  const int by   = blockIdx.y;    // 0..15  h tile (8)
  const int b    = blockIdx.z;    // 0..7
  const int lane = tid & 63;
  const int wave = tid >> 6;
  const int wm   = wave >> 1;     // 0..1
  const int wn   = wave & 1;      // 0..1
  const int l15  = lane & 15;
  const int quad = lane >> 4;

  // Issue tap-0 B loads first: async direct-to-LDS, complete under x staging.
  #pragma unroll
  for (int i = 0; i < 8; ++i) {
    int c = (tid + i * 256) * 16;   // byte offset; wave-uniform base + lane*16
    GLD_LDS16((const char*)vt + c, (char*)lds_w + c);
  }

  // Stage x halo tile directly from f32 NCHW: transpose + convert + swizzle.
  #pragma unroll 1
  for (int i = 0; i < 5; ++i) {        // 1280 (hh,ic) slots / 256 threads
    int slot = tid + i * 256;
    int hh = slot >> 7, ic = slot & 127;
    int h  = by * 8 + hh - 1;
    float vals[18];
    if ((unsigned)h < 128u) {
      const float* xr = x + ((size_t)(b * 128 + ic) * 128 + h) * 128 + bx * 16;
      #pragma unroll
      for (int q = 0; q < 4; ++q) {
        float4 v4 = *(const float4*)(xr + 4 * q);
        vals[1 + 4 * q] = v4.x; vals[2 + 4 * q] = v4.y;
        vals[3 + 4 * q] = v4.z; vals[4 + 4 * q] = v4.w;
      }
      vals[0]  = (bx == 0) ? 0.f : xr[-1];   // w = bx*16-1
      vals[17] = (bx == 7) ? 0.f : xr[16];   // w = bx*16+16
    } else {
      #pragma unroll
      for (int q = 0; q < 18; ++q) vals[q] = 0.f;   // top/bottom padding row
    }
    const int icq = ic >> 3, icr = (ic & 7) * 2;
    #pragma unroll
    for (int ww = 0; ww < 18; ++ww) {
      int row  = hh * 18 + ww;
      int cidx = (row * 16 + icq) ^ (row & 7);     // same swizzle as the read side
      *(unsigned short*)((char*)lds_x + cidx * 16 + icr) = f2bf(vals[ww]);
    }
  }
  asm volatile("s_waitcnt vmcnt(0)" ::: "memory");
  __syncthreads();                 // x tile AND tap-0 B ready

  f32x4 acc[4][4];
  #pragma unroll
  for (int mi = 0; mi < 4; ++mi)
    #pragma unroll
    for (int ni = 0; ni < 4; ++ni)
      acc[mi][ni] = f32x4{0.f, 0.f, 0.f, 0.f};

  #pragma unroll
  for (int t = 0; t < 9; ++t) {
    const int dh = t / 3, dw = t % 3;
    int rowb[4];
    #pragma unroll
    for (int mi = 0; mi < 4; ++mi)
      rowb[mi] = (wm * 4 + mi + dh) * 18 + l15 + dw;   // per-lane LDS row
    #pragma unroll
    for (int ks = 0; ks < 4; ++ks) {                   // K = 128 = 4 x 32
      short8 bb[4];
      #pragma unroll
      for (int ni = 0; ni < 4; ++ni)                   // contiguous 1KB/wave, conflict-free
        bb[ni] = *(const short8*)(lds_w + (ks * 8 + wn * 4 + ni) * 512 + lane * 8);
      short8 a[4];
      #pragma unroll
      for (int mi = 0; mi < 4; ++mi) {
        int row = rowb[mi];
        int off = row * 256 + ((ks * 64 + quad * 16) ^ ((row & 7) << 4));  // swizzled read
        a[mi] = *(const short8*)((const char*)lds_x + off);
      }
      #pragma unroll
      for (int mi = 0; mi < 4; ++mi)
        #pragma unroll
        for (int ni = 0; ni < 4; ++ni)
          acc[mi][ni] = __builtin_amdgcn_mfma_f32_16x16x32_bf16(a[mi], bb[ni], acc[mi][ni], 0, 0, 0);
    }
    if (t < 8) {
      __syncthreads();             // all waves done reading lds_w for tap t
      const char* src = (const char*)vt + (size_t)(t + 1) * 32768;
      #pragma unroll
      for (int i = 0; i < 8; ++i) {
        int c = (tid + i * 256) * 16;
        GLD_LDS16(src + c, (char*)lds_w + c);
      }
      asm volatile("s_waitcnt vmcnt(0)" ::: "memory");
      __syncthreads();             // tap t+1 B ready
    }
  }

  // Epilogue: D row = quad*4+reg (pixel w offset), col = l15 (oc). float4 stores, w-contiguous.
  const int h0 = by * 8, w0 = bx * 16;
  #pragma unroll
  for (int ni = 0; ni < 4; ++ni) {
    int oc = (wn * 4 + ni) * 16 + l15;
    float bv = beff[oc];
    #pragma unroll
    for (int mi = 0; mi < 4; ++mi) {
      int h = h0 + wm * 4 + mi;
      int w = w0 + quad * 4;
      f32x4 v = acc[mi][ni];
      v[0] += bv; v[1] += bv; v[2] += bv; v[3] += bv;
      *(f32x4*)(out + ((size_t)(b * 128 + oc) * 128 + h) * 128 + w) = v;
    }
  }
}

extern "C" void kernel_launch(void* const* d_in, const int* in_sizes, int n_in,
                              void* d_out, int out_size, void* d_ws, size_t ws_size,
                              hipStream_t stream) {
  (void)in_sizes; (void)n_in; (void)out_size; (void)ws_size;
  const float* x    = (const float*)d_in[0];   // [8][128][128][128]
  const float* W    = (const float*)d_in[1];   // [8][16][16][3][3]
  const float* bias = (const float*)d_in[2];   // [8][16]
  float* out = (float*)d_out;                  // [8][128][128][128]

  const size_t VT_BYTES = (size_t)9 * 4 * 8 * 512 * 2;   // 294,912
  unsigned short* vt = (unsigned short*)d_ws;
  float* beff = (float*)((char*)d_ws + VT_BYTES);

  prep_kernel<<<dim3(576), 256, 0, stream>>>(W, bias, vt, beff);       // vt + beff
  conv_kernel<<<dim3(8, 16, 8), 256, 0, stream>>>(x, vt, beff, out);   // fused xpose+conv
}

// Round 12
// 152.638 us; speedup vs baseline: 1.2954x; 1.0811x over previous
//
#include <hip/hip_runtime.h>
#include <stdint.h>
#include <stddef.h>

// GA3 conv2d == one dense 3x3 conv with sign-permuted weights:
//   out[b, c*8+m, h, w] = bias_eff[c*8+m]
//     + sum_{cin,k,kh,kw} s(m,k) * W[j(m,k),c,cin,kh,kw] * x[b, cin*8+k, h+kh-1, w+kw-1]
// bf16 MFMA implicit GEMM over 9 taps (K=128 each).
// R9: revert R8 fusion (split pipeline kernel-sum 77us < fused 84us). conv gets
// half-tap double-buffered lds_w (2 x 16KB, same 78.8KB total): issue-early /
// compute / wait-late (T3 minimum 2-phase) so each B-load batch hides under 32
// MFMAs instead of stalling naked between two barriers (R6's per-tap drain).
// xpose/prep byte-identical to R6 (best measured split: conv 48us).

typedef __attribute__((ext_vector_type(8))) short short8;   // 8 x bf16 (4 VGPRs)
typedef __attribute__((ext_vector_type(4))) float f32x4;    // MFMA accumulator

#define GLD_LDS16(gsrc, ldst) __builtin_amdgcn_global_load_lds( \
    (const __attribute__((address_space(1))) void*)(gsrc),      \
    (__attribute__((address_space(3))) void*)(ldst), 16, 0, 0)

// j(m,k) and s(m,k): unique j with S[m,j,k]!=0, transcribed from _TERMS.
__device__ __constant__ int c_J[64] = {
  0,1,2,3,4,5,6,7,
  1,0,4,6,2,7,3,5,
  2,4,0,5,1,3,7,6,
  3,6,5,0,7,2,1,4,
  4,2,1,7,0,6,5,3,
  5,7,3,2,6,0,4,1,
  6,3,7,1,5,4,0,2,
  7,5,6,4,3,1,2,0
};
__device__ __constant__ float c_Sg[64] = {
  1,1,1,1,-1,-1,-1,-1,
  1,1,-1,-1,1,-1,1,-1,
  1,1,1,-1,-1,1,1,1,
  1,1,1,1,-1,-1,-1,-1,
  1,1,-1,1,1,1,-1,1,
  1,1,1,-1,-1,1,1,1,
  1,1,-1,-1,1,-1,1,-1,
  1,1,-1,1,1,1,-1,1
};

__device__ inline unsigned short f2bf(float f) {  // RNE float->bf16
  unsigned int u = __float_as_uint(f);
  u += 0x7FFFu + ((u >> 16) & 1u);
  return (unsigned short)(u >> 16);
}

// ---------------- Prep A: x [8][128][128][128] f32 NCHW -> xt [8][130][130][128] bf16 NHWC
// (padded). One block per (h, b): full 128-w row, all 128 ic. float4 reads,
// LDS [ic][stride 129] (odd stride: both phases 2-way = free), uint2 writes.
// Border zeroing folded in: col 0/129 every block; rows 0/129 in h==0/127 blocks.
__global__ __launch_bounds__(256) void xpose_kernel(const float* __restrict__ x,
                                                    unsigned short* __restrict__ xt) {
  __shared__ unsigned short t[128 * 129];   // 33,024 B
  const int h   = blockIdx.x;       // 0..127
  const int b   = blockIdx.y;       // 0..7
  const int tid = threadIdx.x;
  // Phase 1: global float4 -> bf16 -> LDS [ic][w]
  #pragma unroll
  for (int i = 0; i < 16; ++i) {
    int idx = tid + i * 256;        // 0..4095 = 128 ic * 32 w-quads
    int ic = idx >> 5, wq = idx & 31;
    const float4 v = *(const float4*)(x + ((size_t)(b * 128 + ic) * 128 + h) * 128 + 4 * wq);
    unsigned short* d = t + ic * 129 + 4 * wq;
    d[0] = f2bf(v.x); d[1] = f2bf(v.y); d[2] = f2bf(v.z); d[3] = f2bf(v.w);
  }
  // Border: cols 0 and 129 of this row (h+1)
  if (tid < 128) {
    int c = tid >> 6, u = tid & 63;
    *(unsigned int*)(xt + ((size_t)(b * 130 + h + 1) * 130 + c * 129) * 128 + 2 * u) = 0u;
  }
  // Border: rows 0 / 129 (only the h==0 / h==127 blocks)
  if (h == 0 || h == 127) {
    int row = (h == 0) ? 0 : 129;
    for (int i = 0; i < 33; ++i) {
      int idx = tid + i * 256;      // 130 px * 64 uints = 8320
      if (idx < 8320) {
        int w = idx >> 6, u = idx & 63;
        *(unsigned int*)(xt + ((size_t)(b * 130 + row) * 130 + w) * 128 + 2 * u) = 0u;
      }
    }
  }
  __syncthreads();
  // Phase 2: LDS -> global, ic-contiguous uint2 (4 ic per lane per iter)
  #pragma unroll
  for (int i = 0; i < 16; ++i) {
    int idx = tid + i * 256;        // 0..4095 = 128 w * 32 ic-quads
    int w = idx >> 5, p4 = idx & 31;
    unsigned int s0 = t[(4 * p4 + 0) * 129 + w];
    unsigned int s1 = t[(4 * p4 + 1) * 129 + w];
    unsigned int s2 = t[(4 * p4 + 2) * 129 + w];
    unsigned int s3 = t[(4 * p4 + 3) * 129 + w];
    uint2 o; o.x = s0 | (s1 << 16); o.y = s2 | (s3 << 16);
    *(uint2*)(xt + ((size_t)(b * 130 + h + 1) * 130 + (w + 1)) * 128 + 4 * p4) = o;
  }
}

// ---------------- Prep B: vt[t][ks][ocb][lane][8] bf16 — tap t's 32KB block is a flat
// [ks][ocb][512-short] region; conv stages it in two 16KB halves (ks01 / ks23):
// oc = ocb*16 + (lane&15), ic = ks*32 + (lane>>4)*8 + e.  Also bias_eff[128] f32.
__global__ __launch_bounds__(256) void prep_kernel(const float* __restrict__ W,
                                                   const float* __restrict__ bias,
                                                   unsigned short* __restrict__ vt,
                                                   float* __restrict__ beff) {
  int gid = blockIdx.x * 256 + threadIdx.x;   // 9*128*128 = 147456 threads exactly
  int t   = gid >> 14;
  int rem = gid & 16383;
  int oc  = rem >> 7;
  int ic  = rem & 127;
  int m = oc & 7, cout = oc >> 3;
  int k = ic & 7, cin = ic >> 3;
  int j = c_J[m * 8 + k];
  float s = c_Sg[m * 8 + k];
  float val = s * W[((j * 16 + cout) * 16 + cin) * 9 + t];
  int ks = ic >> 5, quad = (ic >> 3) & 3, e = ic & 7;
  int ocb = oc >> 4, l15 = oc & 15;
  vt[(size_t)((t * 4 + ks) * 8 + ocb) * 512 + (quad * 16 + l15) * 8 + e] = f2bf(val);
  if (gid < 128) {
    int m2 = gid & 7, cout2 = gid >> 3;
    float acc = 0.f;
    #pragma unroll
    for (int kk = 0; kk < 8; ++kk)
      acc += c_Sg[m2 * 8 + kk] * bias[c_J[m2 * 8 + kk] * 16 + cout2];
    beff[gid] = acc;
  }
}

// ---------------- Main: tap-decomposed implicit GEMM, bf16 MFMA 16x16x32 ----------------
// Block: 256 thr = 4 waves. Tile: 8 rows x 16 cols of output pixels x all 128 oc.
// lds_x XOR-swizzled: 16B chunk c stored at c ^ ((c>>4)&7)  (row = c>>4 = hh*18+ww).
// B: half-tap (16KB) double buffer via global_load_lds, issue-early/wait-late:
//   prologue: stage W0=ks01(0) + A; vm0; bar
//   loop t:   stage W1=ks23(t); MFMA ks01(t) from W0; vm0; bar;
//             stage W0=ks01(t+1); MFMA ks23(t) from W1; vm0; bar
// Each load batch hides under 32 MFMAs; vmcnt(0) is exact (1 batch outstanding).
// LDS 45+2x16=78.8KB -> 2 blocks/CU.
__global__ __launch_bounds__(256) void conv_kernel(const unsigned short* __restrict__ xt,
                                                   const unsigned short* __restrict__ vt,
                                                   const float* __restrict__ beff,
                                                   float* __restrict__ out) {
  __shared__ __align__(16) unsigned short lds_x[10 * 18 * 128]; // halo [hh][ww][ic], 45 KiB
  __shared__ __align__(16) unsigned short lds_w[2][64 * 128];   // two half-tap buffers, 16 KiB each
  const int tid  = threadIdx.x;
  const int bx   = blockIdx.x;    // 0..7   w tile (16)
  const int by   = blockIdx.y;    // 0..15  h tile (8)
  const int b    = blockIdx.z;    // 0..7
  const int lane = tid & 63;
  const int wave = tid >> 6;
  const int wm   = wave >> 1;     // 0..1
  const int wn   = wave & 1;      // 0..1
  const int l15  = lane & 15;
  const int quad = lane >> 4;

#define STAGE_HALF(DST, SRCOFF)                                         \
  {                                                                     \
    const char* s_ = (const char*)vt + (SRCOFF);                        \
    _Pragma("unroll")                                                   \
    for (int i_ = 0; i_ < 4; ++i_) {                                    \
      int c_ = (tid + i_ * 256) * 16;                                   \
      GLD_LDS16(s_ + c_, (char*)(DST) + c_);                            \
    }                                                                   \
  }

#define HALF_COMPUTE(WBUF, KS0)                                         \
  {                                                                     \
    _Pragma("unroll")                                                   \
    for (int kk = 0; kk < 2; ++kk) {                                    \
      const int ks = (KS0) + kk;                                        \
      short8 bb[4];                                                     \
      _Pragma("unroll")                                                 \
      for (int ni = 0; ni < 4; ++ni)                                    \
        bb[ni] = *(const short8*)((WBUF) + (kk * 8 + wn * 4 + ni) * 512 + lane * 8); \
      short8 a[4];                                                      \
      _Pragma("unroll")                                                 \
      for (int mi = 0; mi < 4; ++mi) {                                  \
        int row = rowb[mi];                                             \
        int off = row * 256 + ((ks * 64 + quad * 16) ^ ((row & 7) << 4)); \
        a[mi] = *(const short8*)((const char*)lds_x + off);             \
      }                                                                 \
      _Pragma("unroll")                                                 \
      for (int mi = 0; mi < 4; ++mi)                                    \
        _Pragma("unroll")                                               \
        for (int ni = 0; ni < 4; ++ni)                                  \
          acc[mi][ni] = __builtin_amdgcn_mfma_f32_16x16x32_bf16(a[mi], bb[ni], acc[mi][ni], 0, 0, 0); \
    }                                                                   \
  }

  // Prologue: issue tap-0 ks01 into W0 (async, rides under A staging).
  STAGE_HALF(lds_w[0], 0);

  // Stage x halo tile (rows by*8..+9, cols bx*16..+17, 128 ic) = 2880 x 16B chunks,
  // swizzled on the write side.
  {
    const unsigned short* xb = xt + ((size_t)(b * 130 + by * 8) * 130 + bx * 16) * 128;
    #pragma unroll
    for (int i = 0; i < 11; ++i) {
      int c  = tid + i * 256;
      int hh = c / 288;            // 288 chunks per halo row (18*128*2B/16B)
      int r  = c - hh * 288;
      uint4 v = *((const uint4*)(xb + (size_t)hh * (130 * 128)) + r);
      ((uint4*)lds_x)[c ^ ((c >> 4) & 7)] = v;
    }
    if (tid < 64) {                // tail: chunks 2816..2879
      int c  = tid + 2816;
      int hh = c / 288;
      int r  = c - hh * 288;
      uint4 v = *((const uint4*)(xb + (size_t)hh * (130 * 128)) + r);
      ((uint4*)lds_x)[c ^ ((c >> 4) & 7)] = v;
    }
  }
  asm volatile("s_waitcnt vmcnt(0)" ::: "memory");
  __syncthreads();                 // x tile AND W0 (tap0 ks01) ready

  f32x4 acc[4][4];
  #pragma unroll
  for (int mi = 0; mi < 4; ++mi)
    #pragma unroll
    for (int ni = 0; ni < 4; ++ni)
      acc[mi][ni] = f32x4{0.f, 0.f, 0.f, 0.f};

  #pragma unroll
  for (int t = 0; t < 9; ++t) {
    const int dh = t / 3, dw = t % 3;
    int rowb[4];
    #pragma unroll
    for (int mi = 0; mi < 4; ++mi)
      rowb[mi] = (wm * 4 + mi + dh) * 18 + l15 + dw;   // per-lane LDS row

    STAGE_HALF(lds_w[1], (size_t)t * 32768 + 16384);   // ks23(t), hides under:
    HALF_COMPUTE(lds_w[0], 0)                          // 32 MFMA on ks01(t)
    asm volatile("s_waitcnt vmcnt(0)" ::: "memory");
    __syncthreads();                                   // W1 ready; W0 free

    if (t < 8) STAGE_HALF(lds_w[0], (size_t)(t + 1) * 32768);  // ks01(t+1), hides under:
    HALF_COMPUTE(lds_w[1], 2)                          // 32 MFMA on ks23(t)
    if (t < 8) {
      asm volatile("s_waitcnt vmcnt(0)" ::: "memory");
      __syncthreads();                                 // W0 ready; W1 free
    }
  }

  // Epilogue: D row = quad*4+reg (pixel w offset), col = l15 (oc). float4 stores, w-contiguous.
  const int h0 = by * 8, w0 = bx * 16;
  #pragma unroll
  for (int ni = 0; ni < 4; ++ni) {
    int oc = (wn * 4 + ni) * 16 + l15;
    float bv = beff[oc];
    #pragma unroll
    for (int mi = 0; mi < 4; ++mi) {
      int h = h0 + wm * 4 + mi;
      int w = w0 + quad * 4;
      f32x4 v = acc[mi][ni];
      v[0] += bv; v[1] += bv; v[2] += bv; v[3] += bv;
      *(f32x4*)(out + ((size_t)(b * 128 + oc) * 128 + h) * 128 + w) = v;
    }
  }
#undef STAGE_HALF
#undef HALF_COMPUTE
}

extern "C" void kernel_launch(void* const* d_in, const int* in_sizes, int n_in,
                              void* d_out, int out_size, void* d_ws, size_t ws_size,
                              hipStream_t stream) {
  (void)in_sizes; (void)n_in; (void)out_size; (void)ws_size;
  const float* x    = (const float*)d_in[0];   // [8][128][128][128]
  const float* W    = (const float*)d_in[1];   // [8][16][16][3][3]
  const float* bias = (const float*)d_in[2];   // [8][16]
  float* out = (float*)d_out;                  // [8][128][128][128]

  const size_t XT_BYTES = (size_t)8 * 130 * 130 * 128 * 2;   // 34,611,200
  const size_t VT_BYTES = (size_t)9 * 4 * 8 * 512 * 2;       //    294,912
  unsigned short* xt = (unsigned short*)d_ws;
  unsigned short* vt = (unsigned short*)((char*)d_ws + XT_BYTES);
  float* beff = (float*)((char*)d_ws + XT_BYTES + VT_BYTES);

  prep_kernel<<<dim3(576), 256, 0, stream>>>(W, bias, vt, beff);       // vt + beff
  xpose_kernel<<<dim3(128, 8), 256, 0, stream>>>(x, xt);               // incl. border zero
  conv_kernel<<<dim3(8, 16, 8), 256, 0, stream>>>(xt, vt, beff, out);
}